// Round 1
// baseline (72.707 us; speedup 1.0000x reference)
//
#include <hip/hip_runtime.h>

// Local NCC loss: mean over voxels of cross^2 / (I_var*J_var + 1e-5)
// where cross/I_var/J_var derive from 5x5x5 box sums of I, J, I^2, J^2, I*J.
// Shapes: real/fake = (2,1,160,160,160) f32, SAME zero padding. Output: 1 f32.

#define DIM 160
#define TW 32          // output tile width  (W, contiguous)
#define TH 16          // output tile height (H)
#define TD 32          // depth chunk per block
#define RW (TW + 4)    // 36: halo tile width
#define RH (TH + 4)    // 20: halo tile height
#define NBLK ((DIM / TW) * (DIM / TH) * 2 * (DIM / TD))  // 5*10*10 = 500

__global__ __launch_bounds__(512) void ncc_main(const float* __restrict__ real,
                                                const float* __restrict__ fake,
                                                float* __restrict__ partials) {
    __shared__ float rawI[RH][RW];
    __shared__ float rawJ[RH][RW];
    __shared__ float hs[5][TH][RW];
    __shared__ float wsum[8];

    const int tw  = threadIdx.x;            // 0..31
    const int th  = threadIdx.y;            // 0..15
    const int tid = th * TW + tw;           // 0..511

    const int w0 = blockIdx.x * TW;
    const int h0 = blockIdx.y * TH;
    const int n  = blockIdx.z / (DIM / TD);
    const int d0 = (blockIdx.z % (DIM / TD)) * TD;

    const size_t nbase = (size_t)n * DIM * DIM * DIM;

    float ring[5][5];
#pragma unroll
    for (int q = 0; q < 5; ++q)
#pragma unroll
        for (int r = 0; r < 5; ++r) ring[q][r] = 0.f;

    float acc = 0.f;

    for (int dd = d0 - 2; dd <= d0 + TD + 1; ++dd) {
        // ---- 1. load halo slab (zero-pad out-of-bounds) ----
        const bool dok = (dd >= 0) & (dd < DIM);
        for (int idx = tid; idx < RH * RW; idx += 512) {
            const int r = idx / RW, c = idx % RW;
            const int h = h0 - 2 + r;
            const int w = w0 - 2 + c;
            float vi = 0.f, vj = 0.f;
            if (dok && (unsigned)h < DIM && (unsigned)w < DIM) {
                const size_t g = nbase + ((size_t)dd * DIM + h) * DIM + w;
                vi = real[g];
                vj = fake[g];
            }
            rawI[r][c] = vi;
            rawJ[r][c] = vj;
        }
        __syncthreads();

        // ---- 2. H-direction 5-sums of the 5 quantities ----
        for (int idx = tid; idx < TH * RW; idx += 512) {
            const int i = idx / RW, x = idx % RW;
            float sI = 0.f, sJ = 0.f, sI2 = 0.f, sJ2 = 0.f, sIJ = 0.f;
#pragma unroll
            for (int r = 0; r < 5; ++r) {
                const float a = rawI[i + r][x];
                const float b = rawJ[i + r][x];
                sI  += a;     sJ  += b;
                sI2 += a * a; sJ2 += b * b; sIJ += a * b;
            }
            hs[0][i][x] = sI;  hs[1][i][x] = sJ;
            hs[2][i][x] = sI2; hs[3][i][x] = sJ2; hs[4][i][x] = sIJ;
        }
        __syncthreads();

        // ---- 3. W-direction 5-sums -> per-thread 2D slab sums into ring ----
        const int slot = ((dd % 5) + 5) % 5;
#pragma unroll
        for (int q = 0; q < 5; ++q) {
            float s = 0.f;
#pragma unroll
            for (int k = 0; k < 5; ++k) s += hs[q][th][tw + k];
            ring[q][slot] = s;
        }

        // ---- 4. emit output at depth dout = dd-2 once window complete ----
        const int dout = dd - 2;
        if (dout >= d0) {   // dout < d0+TD guaranteed by loop bound
            float zs[5];
#pragma unroll
            for (int q = 0; q < 5; ++q) {
                float s = 0.f;
#pragma unroll
                for (int r = 0; r < 5; ++r) s += ring[q][r];
                zs[q] = s;
            }
            const float inv   = 1.0f / 125.0f;
            const float cross = zs[4] - zs[0] * zs[1] * inv;
            const float Iv    = zs[2] - zs[0] * zs[0] * inv;
            const float Jv    = zs[3] - zs[1] * zs[1] * inv;
            const float cc    = cross * cross / (Iv * Jv + 1e-5f);
            acc += cc;
        }
    }

    // ---- block reduction -> one partial per block ----
#pragma unroll
    for (int off = 32; off > 0; off >>= 1)
        acc += __shfl_down(acc, off, 64);
    const int lane = tid & 63, wid = tid >> 6;
    if (lane == 0) wsum[wid] = acc;
    __syncthreads();
    if (tid == 0) {
        float s = 0.f;
        for (int i = 0; i < 8; ++i) s += wsum[i];
        partials[(blockIdx.z * gridDim.y + blockIdx.y) * gridDim.x + blockIdx.x] = s;
    }
}

__global__ void ncc_reduce(const float* __restrict__ partials, float* __restrict__ out) {
    double s = 0.0;
    for (int i = threadIdx.x; i < NBLK; i += 64) s += (double)partials[i];
#pragma unroll
    for (int off = 32; off > 0; off >>= 1)
        s += __shfl_down(s, off, 64);
    if (threadIdx.x == 0)
        out[0] = (float)(s / (double)(2.0 * DIM * DIM * DIM));
}

extern "C" void kernel_launch(void* const* d_in, const int* in_sizes, int n_in,
                              void* d_out, int out_size, void* d_ws, size_t ws_size,
                              hipStream_t stream) {
    const float* real = (const float*)d_in[0];
    const float* fake = (const float*)d_in[1];
    float* out      = (float*)d_out;
    float* partials = (float*)d_ws;   // 500 floats

    dim3 grid(DIM / TW, DIM / TH, 2 * (DIM / TD));  // (5,10,10)
    dim3 block(TW, TH, 1);                           // 512 threads
    ncc_main<<<grid, block, 0, stream>>>(real, fake, partials);
    ncc_reduce<<<1, 64, 0, stream>>>(partials, out);
}